// Round 2
// baseline (293.703 us; speedup 1.0000x reference)
//
#include <hip/hip_runtime.h>
#include <stdint.h>

#define BATCH 4096
#define IN_DIM 1024
#define HID 1024
#define KDIM 2048      // IN + HID
#define NGATE 4096     // 4 * HID

typedef __attribute__((ext_vector_type(4))) float floatx4;
typedef __attribute__((ext_vector_type(8))) __bf16 bf16x8;
typedef __attribute__((ext_vector_type(8))) unsigned short ushort8;

__device__ __forceinline__ unsigned short f2bf(float f) {
    union { float f; unsigned int u; } v; v.f = f;
    unsigned int u = v.u;
    u += 0x7fffu + ((u >> 16) & 1u);   // RNE; inputs finite
    return (unsigned short)(u >> 16);
}

// ---------------------------------------------------------------------------
// prep: X = [x | h] bf16 (4096 x 2048).
// W: GATE-INTERLEAVED rows: W-row (u*4 + gate) = [w_gate_i[u] | w_gate_h[u]]
// bf16 (4096 x 2048). bias[u*4+g] = b_g_i[u] + b_g_h[u].
// 8 elements per thread: two float4 loads -> one 16B bf16 store.
// ---------------------------------------------------------------------------
__global__ void prep_kernel(
    const float* __restrict__ x,  const float* __restrict__ h,
    const float* __restrict__ wii, const float* __restrict__ wih,
    const float* __restrict__ wfi, const float* __restrict__ wfh,
    const float* __restrict__ wgi, const float* __restrict__ wgh,
    const float* __restrict__ woi, const float* __restrict__ woh,
    const float* __restrict__ bii, const float* __restrict__ bih,
    const float* __restrict__ bfi, const float* __restrict__ bfh,
    const float* __restrict__ bgi, const float* __restrict__ bgh,
    const float* __restrict__ boi, const float* __restrict__ boh,
    unsigned short* __restrict__ Xb,
    unsigned short* __restrict__ Wb,
    float* __restrict__ bias)
{
    const int t = blockIdx.x * blockDim.x + threadIdx.x;   // one 8-elem chunk
    const int XV8 = BATCH * KDIM / 8;                       // 1M chunks for X
    if (t < XV8) {
        const int e = t * 8;
        const int b = e >> 11, k = e & 2047;   // k % 8 == 0: no IN/HID straddle
        const float* src = (k < IN_DIM) ? (x + (size_t)b * IN_DIM + k)
                                        : (h + (size_t)b * HID + (k - IN_DIM));
        float4 v0 = ((const float4*)src)[0];
        float4 v1 = ((const float4*)src)[1];
        ushort8 o = { f2bf(v0.x), f2bf(v0.y), f2bf(v0.z), f2bf(v0.w),
                      f2bf(v1.x), f2bf(v1.y), f2bf(v1.z), f2bf(v1.w) };
        *(ushort8*)(Xb + e) = o;
    } else if (t < 2 * XV8) {
        const int e = (t - XV8) * 8;
        const int r = e >> 11, k = e & 2047;   // r = W-row = u*4 + gate
        const int u = r >> 2, gate = r & 3;
        const float* wi_[4] = { wii, wfi, wgi, woi };
        const float* wh_[4] = { wih, wfh, wgh, woh };
        const float* src = (k < IN_DIM) ? (wi_[gate] + (size_t)u * IN_DIM + k)
                                        : (wh_[gate] + (size_t)u * HID + (k - IN_DIM));
        float4 v0 = ((const float4*)src)[0];
        float4 v1 = ((const float4*)src)[1];
        ushort8 o = { f2bf(v0.x), f2bf(v0.y), f2bf(v0.z), f2bf(v0.w),
                      f2bf(v1.x), f2bf(v1.y), f2bf(v1.z), f2bf(v1.w) };
        *(ushort8*)(Wb + e) = o;
    }
    if (t < NGATE) {
        const int u = t >> 2, g = t & 3;
        const float* bi_[4] = { bii, bfi, bgi, boi };
        const float* bh_[4] = { bih, bfh, bgh, boh };
        bias[t] = bi_[g][u] + bh_[g][u];
    }
}

// ---------------------------------------------------------------------------
// gemm_lstm: preact[m][n] = sum_k X[m][k]*W[n][k] + bias[n], n = u*4+gate.
// 128x128 tile, BK=32, 256 threads (4 waves, 64x64 each, 4x4 MFMA tiles).
// Fused epilogue: activation + cross-lane (i,f,g,o) gather via shfl
// (4 gates of one hid unit sit in 4 consecutive lanes of a quad), then
// c' = f*c + i*g, h' = o*tanh(c'), written straight to out. No G buffer.
// ---------------------------------------------------------------------------
#define GLD16(g, l)                                                          \
    __builtin_amdgcn_global_load_lds(                                        \
        (__attribute__((address_space(1))) void*)(g),                        \
        (__attribute__((address_space(3))) void*)(l), 16, 0, 0)

__global__ __launch_bounds__(256) void gemm_lstm(
    const unsigned short* __restrict__ X,
    const unsigned short* __restrict__ W,
    const float* __restrict__ bias,
    const float* __restrict__ c_in,
    float* __restrict__ out)
{
    __shared__ __align__(16) unsigned short As[128 * 32];
    __shared__ __align__(16) unsigned short Bs[128 * 32];

    const int tid  = threadIdx.x;
    const int wave = tid >> 6;
    const int lane = tid & 63;
    const int quad = lane >> 4, idx = lane & 15;
    const int wm = (wave >> 1) * 64, wn = (wave & 1) * 64;

    const int rowA0 = blockIdx.x * 128;
    const int rowB0 = blockIdx.y * 128;

    const int srow = tid >> 2, skk = (tid & 3) * 8;
    const unsigned short* gA0 = X + (size_t)(rowA0 + srow) * KDIM + skk;
    const unsigned short* gA1 = X + (size_t)(rowA0 + 64 + srow) * KDIM + skk;
    const unsigned short* gB0 = W + (size_t)(rowB0 + srow) * KDIM + skk;
    const unsigned short* gB1 = W + (size_t)(rowB0 + 64 + srow) * KDIM + skk;

    floatx4 acc[4][4] = {};

    for (int k0 = 0; k0 < KDIM; k0 += 32) {
        GLD16(gA0 + k0, As + tid * 8);
        GLD16(gA1 + k0, As + 2048 + tid * 8);
        GLD16(gB0 + k0, Bs + tid * 8);
        GLD16(gB1 + k0, Bs + 2048 + tid * 8);
        __syncthreads();

        bf16x8 af[4], bfr[4];
#pragma unroll
        for (int i = 0; i < 4; ++i)
            af[i] = *(const bf16x8*)(As + (wm + i * 16 + idx) * 32 + quad * 8);
#pragma unroll
        for (int j = 0; j < 4; ++j)
            bfr[j] = *(const bf16x8*)(Bs + (wn + j * 16 + idx) * 32 + quad * 8);
#pragma unroll
        for (int i = 0; i < 4; ++i)
#pragma unroll
            for (int j = 0; j < 4; ++j)
                acc[i][j] = __builtin_amdgcn_mfma_f32_16x16x32_bf16(
                    af[i], bfr[j], acc[i][j], 0, 0, 0);
        __syncthreads();
    }

    // ---- fused LSTM epilogue ----
    // col = rowB0 + wn + j*16 + idx ; gate = col&3 = idx&3 ; u = col>>2.
    // 4-lane group (lane&~3 .. +3) holds gates i,f,g,o of the same (row,u).
    const int g = idx & 3;
    const int lbase = lane & ~3;
    float* __restrict__ out_h = out;
    float* __restrict__ out_c = out + (size_t)BATCH * HID;

#pragma unroll
    for (int j = 0; j < 4; ++j) {
        const int col = rowB0 + wn + j * 16 + idx;
        const int u = col >> 2;
        const float bv = bias[col];
#pragma unroll
        for (int i = 0; i < 4; ++i) {
#pragma unroll
            for (int r = 0; r < 4; ++r) {
                const int row = rowA0 + wm + i * 16 + quad * 4 + r;
                const float v = acc[i][j][r] + bv;
                // gate==2 -> tanh(v) = 2*sigmoid(2v)-1 ; else sigmoid(v)
                const float vv = (g == 2) ? 2.f * v : v;
                const float s  = 1.f / (1.f + __expf(-vv));
                const float a  = (g == 2) ? 2.f * s - 1.f : s;
                const float iv = __shfl(a, lbase + 0, 64);
                const float fv = __shfl(a, lbase + 1, 64);
                const float gv = __shfl(a, lbase + 2, 64);
                const float ov = __shfl(a, lbase + 3, 64);
                const float cv = c_in[(size_t)row * HID + u];
                const float cp = fv * cv + iv * gv;
                const float e2 = __expf(2.f * cp);
                const float th = (e2 - 1.f) / (e2 + 1.f);
                const float hp = ov * th;
                if (g == 0)      out_h[(size_t)row * HID + u] = hp;
                else if (g == 1) out_c[(size_t)row * HID + u] = cp;
            }
        }
    }
}

// ---------------------------------------------------------------------------
extern "C" void kernel_launch(void* const* d_in, const int* in_sizes, int n_in,
                              void* d_out, int out_size, void* d_ws, size_t ws_size,
                              hipStream_t stream) {
    const float* x   = (const float*)d_in[0];
    const float* h   = (const float*)d_in[1];
    const float* c   = (const float*)d_in[2];
    const float* wii = (const float*)d_in[3];
    const float* bii = (const float*)d_in[4];
    const float* wih = (const float*)d_in[5];
    const float* bih = (const float*)d_in[6];
    const float* wfi = (const float*)d_in[7];
    const float* bfi = (const float*)d_in[8];
    const float* wfh = (const float*)d_in[9];
    const float* bfh = (const float*)d_in[10];
    const float* wgi = (const float*)d_in[11];
    const float* bgi = (const float*)d_in[12];
    const float* wgh = (const float*)d_in[13];
    const float* bgh = (const float*)d_in[14];
    const float* woi = (const float*)d_in[15];
    const float* boi = (const float*)d_in[16];
    const float* woh = (const float*)d_in[17];
    const float* boh = (const float*)d_in[18];

    char* ws = (char*)d_ws;
    unsigned short* Xb  = (unsigned short*)ws;                        // 16 MB
    unsigned short* Wb  = (unsigned short*)(ws + ((size_t)16 << 20)); // 16 MB
    float*          bsv = (float*)(ws + ((size_t)32 << 20));          // 16 KB

    const int prep_threads = 2 * BATCH * KDIM / 8;  // 2M
    prep_kernel<<<(prep_threads + 255) / 256, 256, 0, stream>>>(
        x, h, wii, wih, wfi, wfh, wgi, wgh, woi, woh,
        bii, bih, bfi, bfh, bgi, bgh, boi, boh, Xb, Wb, bsv);

    dim3 g2(BATCH / 128, NGATE / 128);
    gemm_lstm<<<g2, 256, 0, stream>>>(Xb, Wb, bsv, c, (float*)d_out);
}

// Round 3
// 255.948 us; speedup vs baseline: 1.1475x; 1.1475x over previous
//
#include <hip/hip_runtime.h>
#include <stdint.h>

#define BATCH 4096
#define IN_DIM 1024
#define HID 1024
#define KDIM 2048      // IN + HID
#define NGATE 4096     // 4 * HID

typedef __attribute__((ext_vector_type(4))) float floatx4;
typedef __attribute__((ext_vector_type(8))) __bf16 bf16x8;
typedef __attribute__((ext_vector_type(8))) unsigned short ushort8;

__device__ __forceinline__ unsigned short f2bf(float f) {
    union { float f; unsigned int u; } v; v.f = f;
    unsigned int u = v.u;
    u += 0x7fffu + ((u >> 16) & 1u);   // RNE; inputs finite
    return (unsigned short)(u >> 16);
}
__device__ __forceinline__ float bf2f(unsigned short s) {
    union { unsigned int u; float f; } v; v.u = ((unsigned int)s) << 16;
    return v.f;
}
__device__ __forceinline__ ushort8 cvt8(const float* __restrict__ src) {
    float4 v0 = ((const float4*)src)[0];
    float4 v1 = ((const float4*)src)[1];
    ushort8 o = { f2bf(v0.x), f2bf(v0.y), f2bf(v0.z), f2bf(v0.w),
                  f2bf(v1.x), f2bf(v1.y), f2bf(v1.z), f2bf(v1.w) };
    return o;
}

// ---------------------------------------------------------------------------
// prep: all source selection is BLOCK-UNIFORM (scalar branch on blockIdx) —
// no per-thread indexed pointer arrays (R1/R2 prep was ~115 µs due to that).
// Block map (256 thr, 8 elems/thr = 2048 elems/block):
//   [0,    2048): x  -> Xb[b][0..1023]        (4M elems)
//   [2048, 4096): h  -> Xb[b][1024..2047]     (4M elems)
//   [4096, 8192): w_m, m=(bid-4096)>>9        (1M elems each)
//                 gate=m>>1, part=m&1 -> Wb row gate*1024+n, col part*1024+k
//   [8192, 8208): bias, 1 elem/thr, gate = block-uniform
// ---------------------------------------------------------------------------
__global__ __launch_bounds__(256) void prep_kernel(
    const float* __restrict__ x,  const float* __restrict__ h,
    const float* __restrict__ wii, const float* __restrict__ wih,
    const float* __restrict__ wfi, const float* __restrict__ wfh,
    const float* __restrict__ wgi, const float* __restrict__ wgh,
    const float* __restrict__ woi, const float* __restrict__ woh,
    const float* __restrict__ bii, const float* __restrict__ bih,
    const float* __restrict__ bfi, const float* __restrict__ bfh,
    const float* __restrict__ bgi, const float* __restrict__ bgh,
    const float* __restrict__ boi, const float* __restrict__ boh,
    unsigned short* __restrict__ Xb,
    unsigned short* __restrict__ Wb,
    float* __restrict__ bias)
{
    const int bid = blockIdx.x;
    const int tid = threadIdx.x;

    if (bid < 2048) {                       // x -> Xb left half
        const int e = (bid * 256 + tid) * 8;        // elem in x
        const int b = e >> 10, k = e & 1023;
        *(ushort8*)(Xb + (size_t)b * KDIM + k) = cvt8(x + e);
    } else if (bid < 4096) {                // h -> Xb right half
        const int e = ((bid - 2048) * 256 + tid) * 8;
        const int b = e >> 10, k = e & 1023;
        *(ushort8*)(Xb + (size_t)b * KDIM + 1024 + k) = cvt8(h + e);
    } else if (bid < 8192) {                // weights
        const int m   = (bid - 4096) >> 9;          // 0..7, block-uniform
        const int off = (bid - 4096) & 511;
        const int e = (off * 256 + tid) * 8;        // elem in w[m]
        const int n = e >> 10, k = e & 1023;
        const float* src;
        switch (m) {                                 // scalar branch
            case 0: src = wii; break; case 1: src = wih; break;
            case 2: src = wfi; break; case 3: src = wfh; break;
            case 4: src = wgi; break; case 5: src = wgh; break;
            case 6: src = woi; break; default: src = woh; break;
        }
        const int gate = m >> 1, part = m & 1;
        *(ushort8*)(Wb + (size_t)(gate * 1024 + n) * KDIM + part * 1024 + k)
            = cvt8(src + e);
    } else {                                // bias: 16 blocks x 256 elems
        const int t = (bid - 8192) * 256 + tid;     // 0..4095
        const int gate = (bid - 8192) >> 2;         // block-uniform (256|1024)
        const int n = t & 1023;
        const float *bi, *bh_;
        switch (gate) {                              // scalar branch
            case 0: bi = bii; bh_ = bih; break;
            case 1: bi = bfi; bh_ = bfh; break;
            case 2: bi = bgi; bh_ = bgh; break;
            default: bi = boi; bh_ = boh; break;
        }
        bias[t] = bi[n] + bh_[n];
    }
}

// ---------------------------------------------------------------------------
// gemm_gates (R1 structure, known 114.5 µs): G[m][n] = act(X.W^T + bias),
// gate-major n = gate*1024 + u. 128x128 tile, BK=32, 4 waves.
// ---------------------------------------------------------------------------
#define GLD16(g, l)                                                          \
    __builtin_amdgcn_global_load_lds(                                        \
        (__attribute__((address_space(1))) void*)(g),                        \
        (__attribute__((address_space(3))) void*)(l), 16, 0, 0)

__global__ __launch_bounds__(256) void gemm_gates(
    const unsigned short* __restrict__ X,
    const unsigned short* __restrict__ W,
    const float* __restrict__ bias,
    unsigned short* __restrict__ G)
{
    __shared__ __align__(16) unsigned short As[128 * 32];
    __shared__ __align__(16) unsigned short Bs[128 * 32];

    const int tid  = threadIdx.x;
    const int wave = tid >> 6;
    const int lane = tid & 63;
    const int quad = lane >> 4, idx = lane & 15;
    const int wm = (wave >> 1) * 64, wn = (wave & 1) * 64;

    const int rowA0 = blockIdx.x * 128;
    const int rowB0 = blockIdx.y * 128;

    const int srow = tid >> 2, skk = (tid & 3) * 8;
    const unsigned short* gA0 = X + (size_t)(rowA0 + srow) * KDIM + skk;
    const unsigned short* gA1 = X + (size_t)(rowA0 + 64 + srow) * KDIM + skk;
    const unsigned short* gB0 = W + (size_t)(rowB0 + srow) * KDIM + skk;
    const unsigned short* gB1 = W + (size_t)(rowB0 + 64 + srow) * KDIM + skk;

    floatx4 acc[4][4] = {};

    for (int k0 = 0; k0 < KDIM; k0 += 32) {
        GLD16(gA0 + k0, As + tid * 8);
        GLD16(gA1 + k0, As + 2048 + tid * 8);
        GLD16(gB0 + k0, Bs + tid * 8);
        GLD16(gB1 + k0, Bs + 2048 + tid * 8);
        __syncthreads();

        bf16x8 af[4], bfr[4];
#pragma unroll
        for (int i = 0; i < 4; ++i)
            af[i] = *(const bf16x8*)(As + (wm + i * 16 + idx) * 32 + quad * 8);
#pragma unroll
        for (int j = 0; j < 4; ++j)
            bfr[j] = *(const bf16x8*)(Bs + (wn + j * 16 + idx) * 32 + quad * 8);
#pragma unroll
        for (int i = 0; i < 4; ++i)
#pragma unroll
            for (int j = 0; j < 4; ++j)
                acc[i][j] = __builtin_amdgcn_mfma_f32_16x16x32_bf16(
                    af[i], bfr[j], acc[i][j], 0, 0, 0);
        __syncthreads();
    }

#pragma unroll
    for (int j = 0; j < 4; ++j) {
        const int col = rowB0 + wn + j * 16 + idx;
        const float bv = bias[col];
        const int gate = col >> 10;            // tile 16-aligned: wave-uniform
#pragma unroll
        for (int i = 0; i < 4; ++i) {
#pragma unroll
            for (int r = 0; r < 4; ++r) {
                const int row = rowA0 + wm + i * 16 + quad * 4 + r;
                const float v = acc[i][j][r] + bv;
                float a;
                if (gate == 2) {               // g-gate: tanh
                    const float e = __expf(2.f * v);
                    a = (e - 1.f) / (e + 1.f);
                } else {                       // i,f,o: sigmoid
                    a = 1.f / (1.f + __expf(-v));
                }
                G[(size_t)row * NGATE + col] = f2bf(a);
            }
        }
    }
}

// ---------------------------------------------------------------------------
// ew: c' = f*c + i*g ; h' = o*tanh(c'); vectorized 8 elems/thread.
// out = [h' (4M) | c' (4M)] fp32
// ---------------------------------------------------------------------------
__global__ __launch_bounds__(256) void ew_kernel(
    const unsigned short* __restrict__ G,
    const float* __restrict__ c,
    float* __restrict__ out)
{
    const int t = (blockIdx.x * 256 + threadIdx.x) * 8;   // 0..4M-1, step 8
    const int b = t >> 10, n = t & 1023;
    const unsigned short* g = G + (size_t)b * NGATE;
    ushort8 iv8 = *(const ushort8*)(g + n);
    ushort8 fv8 = *(const ushort8*)(g + 1024 + n);
    ushort8 gv8 = *(const ushort8*)(g + 2048 + n);
    ushort8 ov8 = *(const ushort8*)(g + 3072 + n);
    float cp[8], hp[8];
#pragma unroll
    for (int e = 0; e < 8; ++e) {
        const float cv = c[t + e];
        const float cpe = bf2f(fv8[e]) * cv + bf2f(iv8[e]) * bf2f(gv8[e]);
        const float e2 = __expf(2.f * cpe);
        cp[e] = cpe;
        hp[e] = bf2f(ov8[e]) * ((e2 - 1.f) / (e2 + 1.f));
    }
    float* oh = out + t;
    float* oc = out + (size_t)BATCH * HID + t;
#pragma unroll
    for (int e = 0; e < 8; ++e) { oh[e] = hp[e]; oc[e] = cp[e]; }
}

// ---------------------------------------------------------------------------
extern "C" void kernel_launch(void* const* d_in, const int* in_sizes, int n_in,
                              void* d_out, int out_size, void* d_ws, size_t ws_size,
                              hipStream_t stream) {
    const float* x   = (const float*)d_in[0];
    const float* h   = (const float*)d_in[1];
    const float* c   = (const float*)d_in[2];
    const float* wii = (const float*)d_in[3];
    const float* bii = (const float*)d_in[4];
    const float* wih = (const float*)d_in[5];
    const float* bih = (const float*)d_in[6];
    const float* wfi = (const float*)d_in[7];
    const float* bfi = (const float*)d_in[8];
    const float* wfh = (const float*)d_in[9];
    const float* bfh = (const float*)d_in[10];
    const float* wgi = (const float*)d_in[11];
    const float* bgi = (const float*)d_in[12];
    const float* wgh = (const float*)d_in[13];
    const float* bgh = (const float*)d_in[14];
    const float* woi = (const float*)d_in[15];
    const float* boi = (const float*)d_in[16];
    const float* woh = (const float*)d_in[17];
    const float* boh = (const float*)d_in[18];

    char* ws = (char*)d_ws;
    unsigned short* Xb  = (unsigned short*)ws;                                // 16 MB
    unsigned short* Wb  = (unsigned short*)(ws + ((size_t)16 << 20));         // 16 MB
    float*          bsv = (float*)(ws + ((size_t)32 << 20));                  // 16 KB
    unsigned short* G   = (unsigned short*)(ws + ((size_t)32 << 20) + 65536); // 32 MB

    prep_kernel<<<8208, 256, 0, stream>>>(
        x, h, wii, wih, wfi, wfh, wgi, wgh, woi, woh,
        bii, bih, bfi, bfh, bgi, bgh, boi, boh, Xb, Wb, bsv);

    dim3 g2(BATCH / 128, NGATE / 128);
    gemm_gates<<<g2, 256, 0, stream>>>(Xb, Wb, bsv, G);

    ew_kernel<<<BATCH * HID / (256 * 8), 256, 0, stream>>>(G, c, (float*)d_out);
}

// Round 4
// 242.259 us; speedup vs baseline: 1.2124x; 1.0565x over previous
//
#include <hip/hip_runtime.h>
#include <stdint.h>

#define BATCH 4096
#define IN_DIM 1024
#define HID 1024
#define KDIM 2048      // IN + HID
#define NGATE 4096     // 4 * HID
#define EPITCH 136     // epilogue LDS row pitch (shorts); 136*2B = 16B-aligned

typedef __attribute__((ext_vector_type(4))) float floatx4;
typedef __attribute__((ext_vector_type(8))) __bf16 bf16x8;
typedef __attribute__((ext_vector_type(8))) unsigned short ushort8;

__device__ __forceinline__ unsigned short f2bf(float f) {
    union { float f; unsigned int u; } v; v.f = f;
    unsigned int u = v.u;
    u += 0x7fffu + ((u >> 16) & 1u);   // RNE; inputs finite
    return (unsigned short)(u >> 16);
}
__device__ __forceinline__ float bf2f(unsigned short s) {
    union { unsigned int u; float f; } v; v.u = ((unsigned int)s) << 16;
    return v.f;
}
__device__ __forceinline__ ushort8 cvt8(const float* __restrict__ src) {
    float4 v0 = ((const float4*)src)[0];
    float4 v1 = ((const float4*)src)[1];
    ushort8 o = { f2bf(v0.x), f2bf(v0.y), f2bf(v0.z), f2bf(v0.w),
                  f2bf(v1.x), f2bf(v1.y), f2bf(v1.z), f2bf(v1.w) };
    return o;
}

// ---------------------------------------------------------------------------
// prep (block-uniform source routing):
//   X  = [x | h] bf16 (4096 x 2048)
//   W  = GATE-INTERLEAVED rows: W-row (u*4+gate) = [w_gate_i[u] | w_gate_h[u]]
//   bias[u*4+gate] = b_gate_i[u] + b_gate_h[u]
// ---------------------------------------------------------------------------
__global__ __launch_bounds__(256) void prep_kernel(
    const float* __restrict__ x,  const float* __restrict__ h,
    const float* __restrict__ wii, const float* __restrict__ wih,
    const float* __restrict__ wfi, const float* __restrict__ wfh,
    const float* __restrict__ wgi, const float* __restrict__ wgh,
    const float* __restrict__ woi, const float* __restrict__ woh,
    const float* __restrict__ bii, const float* __restrict__ bih,
    const float* __restrict__ bfi, const float* __restrict__ bfh,
    const float* __restrict__ bgi, const float* __restrict__ bgh,
    const float* __restrict__ boi, const float* __restrict__ boh,
    unsigned short* __restrict__ Xb,
    unsigned short* __restrict__ Wb,
    float* __restrict__ bias)
{
    const int bid = blockIdx.x;
    const int tid = threadIdx.x;

    if (bid < 2048) {                       // x -> Xb left half
        const int e = (bid * 256 + tid) * 8;
        const int b = e >> 10, k = e & 1023;
        *(ushort8*)(Xb + (size_t)b * KDIM + k) = cvt8(x + e);
    } else if (bid < 4096) {                // h -> Xb right half
        const int e = ((bid - 2048) * 256 + tid) * 8;
        const int b = e >> 10, k = e & 1023;
        *(ushort8*)(Xb + (size_t)b * KDIM + 1024 + k) = cvt8(h + e);
    } else if (bid < 8192) {                // weights -> interleaved W rows
        const int m   = (bid - 4096) >> 9;          // 0..7, block-uniform
        const int off = (bid - 4096) & 511;
        const int e = (off * 256 + tid) * 8;
        const int n = e >> 10, k = e & 1023;
        const float* src;
        switch (m) {
            case 0: src = wii; break; case 1: src = wih; break;
            case 2: src = wfi; break; case 3: src = wfh; break;
            case 4: src = wgi; break; case 5: src = wgh; break;
            case 6: src = woi; break; default: src = woh; break;
        }
        const int gate = m >> 1, part = m & 1;
        *(ushort8*)(Wb + (size_t)(n * 4 + gate) * KDIM + part * 1024 + k)
            = cvt8(src + e);
    } else {                                // bias: 16 blocks x 256 elems
        const int t = (bid - 8192) * 256 + tid;     // 0..4095 = gate*1024+n
        const int gate = (bid - 8192) >> 2;         // block-uniform
        const int n = t & 1023;
        const float *bi, *bh_;
        switch (gate) {
            case 0: bi = bii; bh_ = bih; break;
            case 1: bi = bfi; bh_ = bfh; break;
            case 2: bi = bgi; bh_ = bgh; break;
            default: bi = boi; bh_ = boh; break;
        }
        bias[n * 4 + gate] = bi[n] + bh_[n];
    }
}

// ---------------------------------------------------------------------------
// gemm_lstm: preact = X.W^T + bias, cols interleaved (col = u*4+gate).
// 128x128 tile, BK=32, 4 waves. Fused epilogue:
//  stage 1: bias+activation per acc element -> bf16 into LDS tile E[128][136]
//           (aliases As/Bs, safe after final K-loop barrier)
//  stage 2: each thread re-reads 4 u's worth of (i,f,g,o) for one row,
//           computes c'=f*c+i*g, h'=o*tanh(c'), writes coalesced float4.
// No G buffer, no ew kernel, no partial-line stores.
// ---------------------------------------------------------------------------
#define GLD16(g, l)                                                          \
    __builtin_amdgcn_global_load_lds(                                        \
        (__attribute__((address_space(1))) void*)(g),                        \
        (__attribute__((address_space(3))) void*)(l), 16, 0, 0)

__global__ __launch_bounds__(256) void gemm_lstm(
    const unsigned short* __restrict__ X,
    const unsigned short* __restrict__ W,
    const float* __restrict__ bias,
    const float* __restrict__ c_in,
    float* __restrict__ out)
{
    __shared__ __align__(16) unsigned char smem[128 * EPITCH * 2]; // 34816 B
    unsigned short* As = (unsigned short*)smem;              // 128*32 shorts
    unsigned short* Bs = (unsigned short*)(smem + 8192);     // 128*32 shorts
    unsigned short* E  = (unsigned short*)smem;              // 128 x EPITCH

    const int tid  = threadIdx.x;
    const int wave = tid >> 6;
    const int lane = tid & 63;
    const int quad = lane >> 4, idx = lane & 15;
    const int wm = (wave >> 1) * 64, wn = (wave & 1) * 64;

    const int rowA0 = blockIdx.x * 128;
    const int rowB0 = blockIdx.y * 128;

    const int srow = tid >> 2, skk = (tid & 3) * 8;
    const unsigned short* gA0 = X + (size_t)(rowA0 + srow) * KDIM + skk;
    const unsigned short* gA1 = X + (size_t)(rowA0 + 64 + srow) * KDIM + skk;
    const unsigned short* gB0 = W + (size_t)(rowB0 + srow) * KDIM + skk;
    const unsigned short* gB1 = W + (size_t)(rowB0 + 64 + srow) * KDIM + skk;

    floatx4 acc[4][4] = {};

    for (int k0 = 0; k0 < KDIM; k0 += 32) {
        GLD16(gA0 + k0, As + tid * 8);
        GLD16(gA1 + k0, As + 2048 + tid * 8);
        GLD16(gB0 + k0, Bs + tid * 8);
        GLD16(gB1 + k0, Bs + 2048 + tid * 8);
        __syncthreads();

        bf16x8 af[4], bfr[4];
#pragma unroll
        for (int i = 0; i < 4; ++i)
            af[i] = *(const bf16x8*)(As + (wm + i * 16 + idx) * 32 + quad * 8);
#pragma unroll
        for (int j = 0; j < 4; ++j)
            bfr[j] = *(const bf16x8*)(Bs + (wn + j * 16 + idx) * 32 + quad * 8);
#pragma unroll
        for (int i = 0; i < 4; ++i)
#pragma unroll
            for (int j = 0; j < 4; ++j)
                acc[i][j] = __builtin_amdgcn_mfma_f32_16x16x32_bf16(
                    af[i], bfr[j], acc[i][j], 0, 0, 0);
        __syncthreads();   // also orders last As/Bs reads vs E writes below
    }

    // ---- stage 1: bias + activation -> E (bf16) ----
    const int g = idx & 3;           // gate for this thread's columns
#pragma unroll
    for (int j = 0; j < 4; ++j) {
        const int col = wn + j * 16 + idx;
        const float bv = bias[rowB0 + col];
#pragma unroll
        for (int i = 0; i < 4; ++i) {
#pragma unroll
            for (int r = 0; r < 4; ++r) {
                const int row = wm + i * 16 + quad * 4 + r;
                const float v  = acc[i][j][r] + bv;
                const float vv = (g == 2) ? 2.f * v : v;      // tanh via sigmoid
                const float s  = 1.f / (1.f + __expf(-vv));
                const float a  = (g == 2) ? 2.f * s - 1.f : s;
                E[row * EPITCH + col] = f2bf(a);
            }
        }
    }
    __syncthreads();

    // ---- stage 2: combine + coalesced stores ----
    // pass p: 32 rows; thread -> row_l = p*32 + (tid>>3), u-chunk = (tid&7)*4
    const int tid8 = tid & 7;
    const int rowo = tid >> 3;
    float* __restrict__ out_h = out;
    float* __restrict__ out_c = out + (size_t)BATCH * HID;

#pragma unroll
    for (int p = 0; p < 4; ++p) {
        const int row_l = p * 32 + rowo;
        const int row_g = rowA0 + row_l;
        const int colc  = tid8 * 16;                 // 4 u * 4 gates
        ushort8 e0 = *(const ushort8*)(E + row_l * EPITCH + colc);
        ushort8 e1 = *(const ushort8*)(E + row_l * EPITCH + colc + 8);
        const int u0 = (rowB0 >> 2) + tid8 * 4;
        const float4 cv = *(const float4*)(c_in + (size_t)row_g * HID + u0);

        float cvv[4] = { cv.x, cv.y, cv.z, cv.w };
        float hp[4], cp[4];
#pragma unroll
        for (int d = 0; d < 4; ++d) {
            const ushort8& e = (d < 2) ? e0 : e1;
            const int b = (d & 1) * 4;
            const float iv = bf2f(e[b + 0]);
            const float fv = bf2f(e[b + 1]);
            const float gv = bf2f(e[b + 2]);
            const float ov = bf2f(e[b + 3]);
            const float c2 = fv * cvv[d] + iv * gv;
            const float e2 = __expf(2.f * c2);
            cp[d] = c2;
            hp[d] = ov * ((e2 - 1.f) / (e2 + 1.f));
        }
        float4 hv = { hp[0], hp[1], hp[2], hp[3] };
        float4 cpv = { cp[0], cp[1], cp[2], cp[3] };
        *(float4*)(out_h + (size_t)row_g * HID + u0) = hv;
        *(float4*)(out_c + (size_t)row_g * HID + u0) = cpv;
    }
}

// ---------------------------------------------------------------------------
extern "C" void kernel_launch(void* const* d_in, const int* in_sizes, int n_in,
                              void* d_out, int out_size, void* d_ws, size_t ws_size,
                              hipStream_t stream) {
    const float* x   = (const float*)d_in[0];
    const float* h   = (const float*)d_in[1];
    const float* c   = (const float*)d_in[2];
    const float* wii = (const float*)d_in[3];
    const float* bii = (const float*)d_in[4];
    const float* wih = (const float*)d_in[5];
    const float* bih = (const float*)d_in[6];
    const float* wfi = (const float*)d_in[7];
    const float* bfi = (const float*)d_in[8];
    const float* wfh = (const float*)d_in[9];
    const float* bfh = (const float*)d_in[10];
    const float* wgi = (const float*)d_in[11];
    const float* bgi = (const float*)d_in[12];
    const float* wgh = (const float*)d_in[13];
    const float* bgh = (const float*)d_in[14];
    const float* woi = (const float*)d_in[15];
    const float* boi = (const float*)d_in[16];
    const float* woh = (const float*)d_in[17];
    const float* boh = (const float*)d_in[18];

    char* ws = (char*)d_ws;
    unsigned short* Xb  = (unsigned short*)ws;                        // 16 MB
    unsigned short* Wb  = (unsigned short*)(ws + ((size_t)16 << 20)); // 16 MB
    float*          bsv = (float*)(ws + ((size_t)32 << 20));          // 16 KB

    prep_kernel<<<8208, 256, 0, stream>>>(
        x, h, wii, wih, wfi, wfh, wgi, wgh, woi, woh,
        bii, bih, bfi, bfh, bgi, bgh, boi, boh, Xb, Wb, bsv);

    dim3 g2(BATCH / 128, NGATE / 128);
    gemm_lstm<<<g2, 256, 0, stream>>>(Xb, Wb, bsv, c, (float*)d_out);
}

// Round 5
// 227.450 us; speedup vs baseline: 1.2913x; 1.0651x over previous
//
#include <hip/hip_runtime.h>
#include <stdint.h>

#define BATCH 4096
#define IN_DIM 1024
#define HID 1024
#define KDIM 2048      // IN + HID
#define NGATE 4096     // 4 * HID
#define EPITCH 136     // epilogue LDS row pitch (shorts); 136*2B = 16B-aligned
#define BK 64          // K-tile

typedef __attribute__((ext_vector_type(4))) float floatx4;
typedef __attribute__((ext_vector_type(8))) __bf16 bf16x8;
typedef __attribute__((ext_vector_type(8))) unsigned short ushort8;

__device__ __forceinline__ unsigned short f2bf(float f) {
    union { float f; unsigned int u; } v; v.f = f;
    unsigned int u = v.u;
    u += 0x7fffu + ((u >> 16) & 1u);   // RNE; inputs finite
    return (unsigned short)(u >> 16);
}
__device__ __forceinline__ float bf2f(unsigned short s) {
    union { unsigned int u; float f; } v; v.u = ((unsigned int)s) << 16;
    return v.f;
}
__device__ __forceinline__ ushort8 cvt8(const float* __restrict__ src) {
    float4 v0 = ((const float4*)src)[0];
    float4 v1 = ((const float4*)src)[1];
    ushort8 o = { f2bf(v0.x), f2bf(v0.y), f2bf(v0.z), f2bf(v0.w),
                  f2bf(v1.x), f2bf(v1.y), f2bf(v1.z), f2bf(v1.w) };
    return o;
}

// ---------------------------------------------------------------------------
// prep (block-uniform source routing):
//   X  = [x | h] bf16 (4096 x 2048)
//   W  = GATE-INTERLEAVED rows: W-row (u*4+gate) = [w_gate_i[u] | w_gate_h[u]]
//   bias[u*4+gate] = b_gate_i[u] + b_gate_h[u]
// ---------------------------------------------------------------------------
__global__ __launch_bounds__(256) void prep_kernel(
    const float* __restrict__ x,  const float* __restrict__ h,
    const float* __restrict__ wii, const float* __restrict__ wih,
    const float* __restrict__ wfi, const float* __restrict__ wfh,
    const float* __restrict__ wgi, const float* __restrict__ wgh,
    const float* __restrict__ woi, const float* __restrict__ woh,
    const float* __restrict__ bii, const float* __restrict__ bih,
    const float* __restrict__ bfi, const float* __restrict__ bfh,
    const float* __restrict__ bgi, const float* __restrict__ bgh,
    const float* __restrict__ boi, const float* __restrict__ boh,
    unsigned short* __restrict__ Xb,
    unsigned short* __restrict__ Wb,
    float* __restrict__ bias)
{
    const int bid = blockIdx.x;
    const int tid = threadIdx.x;

    if (bid < 2048) {                       // x -> Xb left half
        const int e = (bid * 256 + tid) * 8;
        const int b = e >> 10, k = e & 1023;
        *(ushort8*)(Xb + (size_t)b * KDIM + k) = cvt8(x + e);
    } else if (bid < 4096) {                // h -> Xb right half
        const int e = ((bid - 2048) * 256 + tid) * 8;
        const int b = e >> 10, k = e & 1023;
        *(ushort8*)(Xb + (size_t)b * KDIM + 1024 + k) = cvt8(h + e);
    } else if (bid < 8192) {                // weights -> interleaved W rows
        const int m   = (bid - 4096) >> 9;          // 0..7, block-uniform
        const int off = (bid - 4096) & 511;
        const int e = (off * 256 + tid) * 8;
        const int n = e >> 10, k = e & 1023;
        const float* src;
        switch (m) {
            case 0: src = wii; break; case 1: src = wih; break;
            case 2: src = wfi; break; case 3: src = wfh; break;
            case 4: src = wgi; break; case 5: src = wgh; break;
            case 6: src = woi; break; default: src = woh; break;
        }
        const int gate = m >> 1, part = m & 1;
        *(ushort8*)(Wb + (size_t)(n * 4 + gate) * KDIM + part * 1024 + k)
            = cvt8(src + e);
    } else {                                // bias: 16 blocks x 256 elems
        const int t = (bid - 8192) * 256 + tid;     // 0..4095 = gate*1024+n
        const int gate = (bid - 8192) >> 2;         // block-uniform
        const int n = t & 1023;
        const float *bi, *bh_;
        switch (gate) {
            case 0: bi = bii; bh_ = bih; break;
            case 1: bi = bfi; bh_ = bfh; break;
            case 2: bi = bgi; bh_ = bgh; break;
            default: bi = boi; bh_ = boh; break;
        }
        bias[n * 4 + gate] = bi[n] + bh_[n];
    }
}

// ---------------------------------------------------------------------------
// gemm_lstm: preact = X.W^T + bias, cols interleaved (col = u*4+gate).
// 128x128 tile, BK=64 (32 K-iters, 32 MFMA per barrier pair), 4 waves.
// LDS layout: row-major chunks of 8 shorts, chunk position XOR-swizzled:
//   store chunk (row, kc) at  row*8 + (kc ^ (row&7))      [16B chunks]
// Staging: GLD16 chunk c = r*256+tid -> row = c>>3, stored kc = c&7,
//   logical kc = (c&7) ^ (row&7); xor folds into per-thread global offset.
// Fragment read: addr = row*64 + ((t*4+quad) ^ (idx&7))*8  (2-way banks).
// Fused epilogue (R4): activation -> E[128][136] bf16 -> combine -> float4.
// ---------------------------------------------------------------------------
#define GLD16(g, l)                                                          \
    __builtin_amdgcn_global_load_lds(                                        \
        (__attribute__((address_space(1))) void*)(g),                        \
        (__attribute__((address_space(3))) void*)(l), 16, 0, 0)

__global__ __launch_bounds__(256) void gemm_lstm(
    const unsigned short* __restrict__ X,
    const unsigned short* __restrict__ W,
    const float* __restrict__ bias,
    const float* __restrict__ c_in,
    float* __restrict__ out)
{
    __shared__ __align__(16) unsigned char smem[128 * EPITCH * 2]; // 34816 B
    unsigned short* As = (unsigned short*)smem;              // 128*64 shorts
    unsigned short* Bs = (unsigned short*)(smem + 16384);    // 128*64 shorts
    unsigned short* E  = (unsigned short*)smem;              // 128 x EPITCH

    const int tid  = threadIdx.x;
    const int wave = tid >> 6;
    const int lane = tid & 63;
    const int quad = lane >> 4, idx = lane & 15;
    const int wm = (wave >> 1) * 64, wn = (wave & 1) * 64;

    const int rowA0 = blockIdx.x * 128;
    const int rowB0 = blockIdx.y * 128;

    // staging: issue r in 0..3, chunk c = r*256+tid; row = r*32 + (tid>>3),
    // logical k-offset = ((tid&7) ^ ((tid>>3)&7)) * 8  (per-thread constant)
    const int srow = tid >> 3;
    const int skk  = ((tid & 7) ^ (srow & 7)) * 8;
    const unsigned short* gA = X + (size_t)(rowA0 + srow) * KDIM + skk;
    const unsigned short* gB = W + (size_t)(rowB0 + srow) * KDIM + skk;
    const size_t rstride = (size_t)32 * KDIM;   // +32 rows per issue

    // fragment read base: row = wm/wn + i*16 + idx
    const int swz = (idx & 7);                  // row&7 for all fragment rows

    floatx4 acc[4][4] = {};

    for (int k0 = 0; k0 < KDIM; k0 += BK) {
#pragma unroll
        for (int r = 0; r < 4; ++r) {
            GLD16(gA + k0 + r * rstride, As + (r * 256 + tid) * 8);
            GLD16(gB + k0 + r * rstride, Bs + (r * 256 + tid) * 8);
        }
        __syncthreads();

        bf16x8 af[4][2], bfr[4][2];
#pragma unroll
        for (int t = 0; t < 2; ++t) {
            const int co = ((t * 4 + quad) ^ swz) * 8;
#pragma unroll
            for (int i = 0; i < 4; ++i)
                af[i][t] = *(const bf16x8*)(As + (wm + i * 16 + idx) * BK + co);
#pragma unroll
            for (int j = 0; j < 4; ++j)
                bfr[j][t] = *(const bf16x8*)(Bs + (wn + j * 16 + idx) * BK + co);
        }
#pragma unroll
        for (int t = 0; t < 2; ++t)
#pragma unroll
            for (int i = 0; i < 4; ++i)
#pragma unroll
                for (int j = 0; j < 4; ++j)
                    acc[i][j] = __builtin_amdgcn_mfma_f32_16x16x32_bf16(
                        af[i][t], bfr[j][t], acc[i][j], 0, 0, 0);
        __syncthreads();   // also orders last As/Bs reads vs E writes below
    }

    // ---- stage 1: bias + activation -> E (bf16) ----
    const int g = idx & 3;           // gate for this thread's columns
#pragma unroll
    for (int j = 0; j < 4; ++j) {
        const int col = wn + j * 16 + idx;
        const float bv = bias[rowB0 + col];
#pragma unroll
        for (int i = 0; i < 4; ++i) {
#pragma unroll
            for (int r = 0; r < 4; ++r) {
                const int row = wm + i * 16 + quad * 4 + r;
                const float v  = acc[i][j][r] + bv;
                const float vv = (g == 2) ? 2.f * v : v;      // tanh via sigmoid
                const float s  = 1.f / (1.f + __expf(-vv));
                const float a  = (g == 2) ? 2.f * s - 1.f : s;
                E[row * EPITCH + col] = f2bf(a);
            }
        }
    }
    __syncthreads();

    // ---- stage 2: combine + coalesced stores ----
    const int tid8 = tid & 7;
    const int rowo = tid >> 3;
    float* __restrict__ out_h = out;
    float* __restrict__ out_c = out + (size_t)BATCH * HID;

#pragma unroll
    for (int p = 0; p < 4; ++p) {
        const int row_l = p * 32 + rowo;
        const int row_g = rowA0 + row_l;
        const int colc  = tid8 * 16;                 // 4 u * 4 gates
        ushort8 e0 = *(const ushort8*)(E + row_l * EPITCH + colc);
        ushort8 e1 = *(const ushort8*)(E + row_l * EPITCH + colc + 8);
        const int u0 = (rowB0 >> 2) + tid8 * 4;
        const float4 cv = *(const float4*)(c_in + (size_t)row_g * HID + u0);

        float cvv[4] = { cv.x, cv.y, cv.z, cv.w };
        float hp[4], cp[4];
#pragma unroll
        for (int d = 0; d < 4; ++d) {
            const ushort8& e = (d < 2) ? e0 : e1;
            const int b = (d & 1) * 4;
            const float iv = bf2f(e[b + 0]);
            const float fv = bf2f(e[b + 1]);
            const float gv = bf2f(e[b + 2]);
            const float ov = bf2f(e[b + 3]);
            const float c2 = fv * cvv[d] + iv * gv;
            const float e2 = __expf(2.f * c2);
            cp[d] = c2;
            hp[d] = ov * ((e2 - 1.f) / (e2 + 1.f));
        }
        float4 hv = { hp[0], hp[1], hp[2], hp[3] };
        float4 cpv = { cp[0], cp[1], cp[2], cp[3] };
        *(float4*)(out_h + (size_t)row_g * HID + u0) = hv;
        *(float4*)(out_c + (size_t)row_g * HID + u0) = cpv;
    }
}

// ---------------------------------------------------------------------------
extern "C" void kernel_launch(void* const* d_in, const int* in_sizes, int n_in,
                              void* d_out, int out_size, void* d_ws, size_t ws_size,
                              hipStream_t stream) {
    const float* x   = (const float*)d_in[0];
    const float* h   = (const float*)d_in[1];
    const float* c   = (const float*)d_in[2];
    const float* wii = (const float*)d_in[3];
    const float* bii = (const float*)d_in[4];
    const float* wih = (const float*)d_in[5];
    const float* bih = (const float*)d_in[6];
    const float* wfi = (const float*)d_in[7];
    const float* bfi = (const float*)d_in[8];
    const float* wfh = (const float*)d_in[9];
    const float* bfh = (const float*)d_in[10];
    const float* wgi = (const float*)d_in[11];
    const float* bgi = (const float*)d_in[12];
    const float* wgh = (const float*)d_in[13];
    const float* bgh = (const float*)d_in[14];
    const float* woi = (const float*)d_in[15];
    const float* boi = (const float*)d_in[16];
    const float* woh = (const float*)d_in[17];
    const float* boh = (const float*)d_in[18];

    char* ws = (char*)d_ws;
    unsigned short* Xb  = (unsigned short*)ws;                        // 16 MB
    unsigned short* Wb  = (unsigned short*)(ws + ((size_t)16 << 20)); // 16 MB
    float*          bsv = (float*)(ws + ((size_t)32 << 20));          // 16 KB

    prep_kernel<<<8208, 256, 0, stream>>>(
        x, h, wii, wih, wfi, wfh, wgi, wgh, woi, woh,
        bii, bih, bfi, bfh, bgi, bgh, boi, boh, Xb, Wb, bsv);

    dim3 g2(BATCH / 128, NGATE / 128);
    gemm_lstm<<<g2, 256, 0, stream>>>(Xb, Wb, bsv, c, (float*)d_out);
}

// Round 6
// 217.590 us; speedup vs baseline: 1.3498x; 1.0453x over previous
//
#include <hip/hip_runtime.h>
#include <stdint.h>

#define BATCH 4096
#define IN_DIM 1024
#define HID 1024
#define KDIM 2048      // IN + HID
#define NGATE 4096     // 4 * HID
#define EPITCH 136     // epilogue LDS row pitch (shorts); 136*2B = 16B-aligned
#define BK 64          // K-tile
#define BM 256         // M-tile
#define BN 128         // N-tile

typedef __attribute__((ext_vector_type(4))) float floatx4;
typedef __attribute__((ext_vector_type(8))) __bf16 bf16x8;
typedef __attribute__((ext_vector_type(8))) unsigned short ushort8;

__device__ __forceinline__ unsigned short f2bf(float f) {
    union { float f; unsigned int u; } v; v.f = f;
    unsigned int u = v.u;
    u += 0x7fffu + ((u >> 16) & 1u);   // RNE; inputs finite
    return (unsigned short)(u >> 16);
}
__device__ __forceinline__ float bf2f(unsigned short s) {
    union { unsigned int u; float f; } v; v.u = ((unsigned int)s) << 16;
    return v.f;
}
__device__ __forceinline__ ushort8 cvt8(const float* __restrict__ src) {
    float4 v0 = ((const float4*)src)[0];
    float4 v1 = ((const float4*)src)[1];
    ushort8 o = { f2bf(v0.x), f2bf(v0.y), f2bf(v0.z), f2bf(v0.w),
                  f2bf(v1.x), f2bf(v1.y), f2bf(v1.z), f2bf(v1.w) };
    return o;
}

// ---------------------------------------------------------------------------
// prep (block-uniform source routing):
//   X  = [x | h] bf16 (4096 x 2048)
//   W  = GATE-INTERLEAVED rows: W-row (u*4+gate) = [w_gate_i[u] | w_gate_h[u]]
//   bias[u*4+gate] = b_gate_i[u] + b_gate_h[u]
// ---------------------------------------------------------------------------
__global__ __launch_bounds__(256) void prep_kernel(
    const float* __restrict__ x,  const float* __restrict__ h,
    const float* __restrict__ wii, const float* __restrict__ wih,
    const float* __restrict__ wfi, const float* __restrict__ wfh,
    const float* __restrict__ wgi, const float* __restrict__ wgh,
    const float* __restrict__ woi, const float* __restrict__ woh,
    const float* __restrict__ bii, const float* __restrict__ bih,
    const float* __restrict__ bfi, const float* __restrict__ bfh,
    const float* __restrict__ bgi, const float* __restrict__ bgh,
    const float* __restrict__ boi, const float* __restrict__ boh,
    unsigned short* __restrict__ Xb,
    unsigned short* __restrict__ Wb,
    float* __restrict__ bias)
{
    const int bid = blockIdx.x;
    const int tid = threadIdx.x;

    if (bid < 2048) {                       // x -> Xb left half
        const int e = (bid * 256 + tid) * 8;
        const int b = e >> 10, k = e & 1023;
        *(ushort8*)(Xb + (size_t)b * KDIM + k) = cvt8(x + e);
    } else if (bid < 4096) {                // h -> Xb right half
        const int e = ((bid - 2048) * 256 + tid) * 8;
        const int b = e >> 10, k = e & 1023;
        *(ushort8*)(Xb + (size_t)b * KDIM + 1024 + k) = cvt8(h + e);
    } else if (bid < 8192) {                // weights -> interleaved W rows
        const int m   = (bid - 4096) >> 9;          // 0..7, block-uniform
        const int off = (bid - 4096) & 511;
        const int e = (off * 256 + tid) * 8;
        const int n = e >> 10, k = e & 1023;
        const float* src;
        switch (m) {
            case 0: src = wii; break; case 1: src = wih; break;
            case 2: src = wfi; break; case 3: src = wfh; break;
            case 4: src = wgi; break; case 5: src = wgh; break;
            case 6: src = woi; break; default: src = woh; break;
        }
        const int gate = m >> 1, part = m & 1;
        *(ushort8*)(Wb + (size_t)(n * 4 + gate) * KDIM + part * 1024 + k)
            = cvt8(src + e);
    } else {                                // bias: 16 blocks x 256 elems
        const int t = (bid - 8192) * 256 + tid;     // 0..4095 = gate*1024+n
        const int gate = (bid - 8192) >> 2;         // block-uniform
        const int n = t & 1023;
        const float *bi, *bh_;
        switch (gate) {
            case 0: bi = bii; bh_ = bih; break;
            case 1: bi = bfi; bh_ = bfh; break;
            case 2: bi = bgi; bh_ = bgh; break;
            default: bi = boi; bh_ = boh; break;
        }
        bias[n * 4 + gate] = bi[n] + bh_[n];
    }
}

// ---------------------------------------------------------------------------
// gemm_lstm: preact = X.W^T + bias, cols interleaved (col = u*4+gate).
// 256x128 tile, BK=64, 512 threads (8 waves, 64x64 each; wave w -> wm=(w>>1)*64,
// wn=(w&1)*64). 6 GLD16/thread/iter (A:4, B:2), 32 MFMA per barrier pair.
// XOR chunk swizzle (R5): store chunk (row,kc) at kc^(row&7); read with
// co = ((t*4+quad)^ (idx&7))*8 — conflict-free (131K confirmed R5).
// Fused epilogue in 2 half-tile phases through E[128][EPITCH] (aliases As/Bs).
// ---------------------------------------------------------------------------
#define GLD16(g, l)                                                          \
    __builtin_amdgcn_global_load_lds(                                        \
        (__attribute__((address_space(1))) void*)(g),                        \
        (__attribute__((address_space(3))) void*)(l), 16, 0, 0)

__global__ __launch_bounds__(512) void gemm_lstm(
    const unsigned short* __restrict__ X,
    const unsigned short* __restrict__ W,
    const float* __restrict__ bias,
    const float* __restrict__ c_in,
    float* __restrict__ out)
{
    __shared__ __align__(16) unsigned char smem[49152];      // 48 KB
    unsigned short* As = (unsigned short*)smem;              // 256*64 shorts, 32 KB
    unsigned short* Bs = (unsigned short*)(smem + 32768);    // 128*64 shorts, 16 KB
    unsigned short* E  = (unsigned short*)smem;              // 128 x EPITCH, 34.8 KB

    const int tid  = threadIdx.x;
    const int wave = tid >> 6;
    const int lane = tid & 63;
    const int quad = lane >> 4, idx = lane & 15;
    const int wm = (wave >> 1) * 64;      // 0,64,128,192
    const int wn = (wave & 1) * 64;       // 0,64

    const int rowA0 = blockIdx.x * BM;
    const int rowB0 = blockIdx.y * BN;

    // staging: srow = tid>>3 (0..63), per-thread k-offset includes xor swizzle
    const int srow = tid >> 3;
    const int skk  = ((tid & 7) ^ (srow & 7)) * 8;
    const unsigned short* gA = X + (size_t)(rowA0 + srow) * KDIM + skk;
    const unsigned short* gB = W + (size_t)(rowB0 + srow) * KDIM + skk;
    const size_t rstride = (size_t)64 * KDIM;   // +64 rows per issue

    const int swz = (idx & 7);

    floatx4 acc[4][4] = {};

    for (int k0 = 0; k0 < KDIM; k0 += BK) {
#pragma unroll
        for (int r = 0; r < 4; ++r)
            GLD16(gA + k0 + r * rstride, As + (r * 512 + tid) * 8);
#pragma unroll
        for (int r = 0; r < 2; ++r)
            GLD16(gB + k0 + r * rstride, Bs + (r * 512 + tid) * 8);
        __syncthreads();

        bf16x8 af[4][2], bfr[4][2];
#pragma unroll
        for (int t = 0; t < 2; ++t) {
            const int co = ((t * 4 + quad) ^ swz) * 8;
#pragma unroll
            for (int i = 0; i < 4; ++i)
                af[i][t] = *(const bf16x8*)(As + (wm + i * 16 + idx) * BK + co);
#pragma unroll
            for (int j = 0; j < 4; ++j)
                bfr[j][t] = *(const bf16x8*)(Bs + (wn + j * 16 + idx) * BK + co);
        }
#pragma unroll
        for (int t = 0; t < 2; ++t)
#pragma unroll
            for (int i = 0; i < 4; ++i)
#pragma unroll
                for (int j = 0; j < 4; ++j)
                    acc[i][j] = __builtin_amdgcn_mfma_f32_16x16x32_bf16(
                        af[i][t], bfr[j][t], acc[i][j], 0, 0, 0);
        __syncthreads();
    }

    // ---- fused epilogue, two half-tile phases (rows 0-127, 128-255) ----
    const int g = idx & 3;
    const int tid8 = tid & 7;
    const int rowo = tid >> 3;           // 0..63
    float* __restrict__ out_h = out;
    float* __restrict__ out_c = out + (size_t)BATCH * HID;

#pragma unroll
    for (int half = 0; half < 2; ++half) {
        // stage 1: waves owning this half write activated gates into E
        if ((wave >> 2) == half) {
            const int wml = wm - half * 128;         // 0 or 64
#pragma unroll
            for (int j = 0; j < 4; ++j) {
                const int col = wn + j * 16 + idx;
                const float bv = bias[rowB0 + col];
#pragma unroll
                for (int i = 0; i < 4; ++i) {
#pragma unroll
                    for (int r = 0; r < 4; ++r) {
                        const int row = wml + i * 16 + quad * 4 + r;
                        const float v  = acc[i][j][r] + bv;
                        const float vv = (g == 2) ? 2.f * v : v;
                        const float s  = 1.f / (1.f + __expf(-vv));
                        const float a  = (g == 2) ? 2.f * s - 1.f : s;
                        E[row * EPITCH + col] = f2bf(a);
                    }
                }
            }
        }
        __syncthreads();

        // stage 2: all 512 threads combine 128 rows (2 passes x 64 rows)
#pragma unroll
        for (int p = 0; p < 2; ++p) {
            const int row_l = p * 64 + rowo;
            const int row_g = rowA0 + half * 128 + row_l;
            const int colc  = tid8 * 16;
            ushort8 e0 = *(const ushort8*)(E + row_l * EPITCH + colc);
            ushort8 e1 = *(const ushort8*)(E + row_l * EPITCH + colc + 8);
            const int u0 = (rowB0 >> 2) + tid8 * 4;
            const float4 cv = *(const float4*)(c_in + (size_t)row_g * HID + u0);

            float cvv[4] = { cv.x, cv.y, cv.z, cv.w };
            float hp[4], cp[4];
#pragma unroll
            for (int d = 0; d < 4; ++d) {
                const ushort8& e = (d < 2) ? e0 : e1;
                const int b = (d & 1) * 4;
                const float iv = bf2f(e[b + 0]);
                const float fv = bf2f(e[b + 1]);
                const float gv = bf2f(e[b + 2]);
                const float ov = bf2f(e[b + 3]);
                const float c2 = fv * cvv[d] + iv * gv;
                const float e2 = __expf(2.f * c2);
                cp[d] = c2;
                hp[d] = ov * ((e2 - 1.f) / (e2 + 1.f));
            }
            float4 hv  = { hp[0], hp[1], hp[2], hp[3] };
            float4 cpv = { cp[0], cp[1], cp[2], cp[3] };
            *(float4*)(out_h + (size_t)row_g * HID + u0) = hv;
            *(float4*)(out_c + (size_t)row_g * HID + u0) = cpv;
        }
        __syncthreads();   // E reads done before next half's writes
    }
}

// ---------------------------------------------------------------------------
extern "C" void kernel_launch(void* const* d_in, const int* in_sizes, int n_in,
                              void* d_out, int out_size, void* d_ws, size_t ws_size,
                              hipStream_t stream) {
    const float* x   = (const float*)d_in[0];
    const float* h   = (const float*)d_in[1];
    const float* c   = (const float*)d_in[2];
    const float* wii = (const float*)d_in[3];
    const float* bii = (const float*)d_in[4];
    const float* wih = (const float*)d_in[5];
    const float* bih = (const float*)d_in[6];
    const float* wfi = (const float*)d_in[7];
    const float* bfi = (const float*)d_in[8];
    const float* wfh = (const float*)d_in[9];
    const float* bfh = (const float*)d_in[10];
    const float* wgi = (const float*)d_in[11];
    const float* bgi = (const float*)d_in[12];
    const float* wgh = (const float*)d_in[13];
    const float* bgh = (const float*)d_in[14];
    const float* woi = (const float*)d_in[15];
    const float* boi = (const float*)d_in[16];
    const float* woh = (const float*)d_in[17];
    const float* boh = (const float*)d_in[18];

    char* ws = (char*)d_ws;
    unsigned short* Xb  = (unsigned short*)ws;                        // 16 MB
    unsigned short* Wb  = (unsigned short*)(ws + ((size_t)16 << 20)); // 16 MB
    float*          bsv = (float*)(ws + ((size_t)32 << 20));          // 16 KB

    prep_kernel<<<8208, 256, 0, stream>>>(
        x, h, wii, wih, wfi, wfh, wgi, wgh, woi, woh,
        bii, bih, bfi, bfh, bgi, bgh, boi, boh, Xb, Wb, bsv);

    dim3 g2(BATCH / BM, NGATE / BN);
    gemm_lstm<<<g2, 512, 0, stream>>>(Xb, Wb, bsv, c, (float*)d_out);
}